// Round 1
// baseline (2194.661 us; speedup 1.0000x reference)
//
#include <hip/hip_runtime.h>

#define NN 16384
#define NE 524288
#define HID 36
#define NCLS 16
#define SPLITK 8
#define KSLICE (NN / SPLITK)
#define RT 256   // rows per block tile in k_gemm1
#define KC 32    // k-chunk staged in LDS

// ---------- CSR build ----------
__global__ void k_zero_int(int* __restrict__ p, int n) {
  int i = blockIdx.x * blockDim.x + threadIdx.x;
  if (i < n) p[i] = 0;
}

__global__ void k_count(const int* __restrict__ dst, int* __restrict__ cnt) {
  int i = blockIdx.x * blockDim.x + threadIdx.x;
  if (i < NE) atomicAdd(&cnt[dst[i]], 1);
}

// single block, 256 threads: exclusive prefix sum over 16384 counts,
// also writes dis[i] = rsqrt(deg_i + 1)  (self-loop included => deg>=1 always)
__global__ void k_scan(const int* __restrict__ cnt, int* __restrict__ off,
                       int* __restrict__ cur, float* __restrict__ dis) {
  __shared__ int part[256];
  const int t = threadIdx.x;
  const int base = t * 64;
  int s = 0;
  for (int i = 0; i < 64; ++i) s += cnt[base + i];
  part[t] = s;
  __syncthreads();
  if (t == 0) {
    int run = 0;
    for (int i = 0; i < 256; ++i) { int v = part[i]; part[i] = run; run += v; }
    off[NN] = run;
  }
  __syncthreads();
  int run = part[t];
  for (int i = 0; i < 64; ++i) {
    int idx = base + i;
    off[idx] = run;
    cur[idx] = run;
    run += cnt[idx];
    dis[idx] = rsqrtf((float)(cnt[idx] + 1));
  }
}

__global__ void k_scatter(const int* __restrict__ src, const int* __restrict__ dst,
                          int* __restrict__ cur, int* __restrict__ esrc) {
  int i = blockIdx.x * blockDim.x + threadIdx.x;
  if (i < NE) {
    int p = atomicAdd(&cur[dst[i]], 1);
    esrc[p] = src[i];
  }
}

// ---------- big GEMM: x[N,N] @ W1[N,36], LDS-staged, split-K partials ----------
// Block: 256 threads, tile = RT(256) rows x KSLICE(2048) k, chunked KC(32) at a time.
// Staging: 8 lanes per row -> each wave-instr fetches 8 aligned, fully-consumed
// 128B segments (16 lines/instr, the coalesced minimum) instead of 64 scattered lines.
// Compute: thread t owns tile-row t; W index is wave-uniform -> scalar K$ loads.
// LDS stride KC+1=33 words => lane stride ≡ 1 (mod 32) => conflict-free reads.
// T14 split: next chunk's global loads issue BEFORE compute; ds_write after barrier.
__global__ void __launch_bounds__(256) k_gemm1(const float* __restrict__ x,
                                               const float* __restrict__ W,
                                               float* __restrict__ part) {
  __shared__ float xs[RT][KC + 1];          // 33.8 KB -> 2 blocks/CU
  const int rb = blockIdx.x & 63;           // 64 row-blocks of 256 rows
  const int s  = blockIdx.x >> 6;           // split-k slice (8)
  const int t  = threadIdx.x;
  const int r0 = rb * RT;
  const int k0 = s * KSLICE;

  const int srow = t >> 3;                  // staging base row (rows advance 32/it)
  const int sc4  = t & 7;                   // which float4 of the 32-float chunk
  const float* __restrict__ xp =
      x + (size_t)(r0 + srow) * NN + (size_t)k0 + (size_t)(sc4 * 4);

  float acc[HID];
#pragma unroll
  for (int c = 0; c < HID; ++c) acc[c] = 0.0f;

  float4 stg[8];
  // prologue: stage chunk 0
#pragma unroll
  for (int it = 0; it < 8; ++it)
    stg[it] = *(const float4*)(xp + (size_t)(it * 32) * NN);
#pragma unroll
  for (int it = 0; it < 8; ++it) {
    float* d = &xs[srow + it * 32][sc4 * 4];
    d[0] = stg[it].x; d[1] = stg[it].y; d[2] = stg[it].z; d[3] = stg[it].w;
  }
  __syncthreads();

  for (int kc = 0; kc < KSLICE; kc += KC) {
    const int nxt = kc + KC;
    if (nxt < KSLICE) {                     // issue next chunk's loads early
#pragma unroll
      for (int it = 0; it < 8; ++it)
        stg[it] = *(const float4*)(xp + nxt + (size_t)(it * 32) * NN);
    }
    // compute current chunk; W access is wave-uniform (scalar loads)
    const float* __restrict__ wk = W + (size_t)(k0 + kc) * HID;
#pragma unroll
    for (int kk = 0; kk < KC; ++kk) {
      const float a = xs[t][kk];
#pragma unroll
      for (int c = 0; c < HID; ++c)
        acc[c] = fmaf(a, wk[kk * HID + c], acc[c]);
    }
    if (nxt < KSLICE) {
      __syncthreads();                      // all reads of xs done
#pragma unroll
      for (int it = 0; it < 8; ++it) {
        float* d = &xs[srow + it * 32][sc4 * 4];
        d[0] = stg[it].x; d[1] = stg[it].y; d[2] = stg[it].z; d[3] = stg[it].w;
      }
      __syncthreads();                      // writes visible before next compute
    }
  }

  float* __restrict__ po = part + (size_t)s * NN * HID + (size_t)(r0 + t) * HID;
#pragma unroll
  for (int c4 = 0; c4 < HID / 4; ++c4)
    ((float4*)po)[c4] = make_float4(acc[4 * c4 + 0], acc[4 * c4 + 1],
                                    acc[4 * c4 + 2], acc[4 * c4 + 3]);
}

__global__ void k_reduce(const float* __restrict__ part, float* __restrict__ o, int n) {
  int i = blockIdx.x * blockDim.x + threadIdx.x;
  if (i < n) {
    float s = 0.0f;
#pragma unroll
    for (int p = 0; p < SPLITK; ++p) s += part[(size_t)p * n + i];
    o[i] = s;
  }
}

// ---------- aggregation: out[i,f] = dis_i * sum_e dis_src * h[src,f] + dis_i^2 * h[i,f] + b[f] ----------
template <int F, bool RELU>
__global__ void k_agg(const float* __restrict__ h, const int* __restrict__ off,
                      const int* __restrict__ esrc, const float* __restrict__ dis,
                      const float* __restrict__ b, float* __restrict__ out) {
  const int tid = blockIdx.x * blockDim.x + threadIdx.x;
  const int i = tid / F;
  const int f = tid - i * F;
  const int beg = off[i], end = off[i + 1];
  float acc = 0.0f;
  for (int j = beg; j < end; ++j) {
    const int s = esrc[j];
    acc = fmaf(dis[s], h[(size_t)s * F + f], acc);
  }
  const float di = dis[i];
  float v = fmaf(di, acc, di * di * h[(size_t)i * F + f]) + b[f];
  if (RELU) v = fmaxf(v, 0.0f);
  out[tid] = v;
}

// ---------- small dense layers ----------
template <int IN, int OUT>
__global__ void k_mm(const float* __restrict__ h, const float* __restrict__ W,
                     float* __restrict__ o) {
  const int tid = blockIdx.x * blockDim.x + threadIdx.x;
  const int i = tid / OUT;
  const int c = tid - i * OUT;
  float acc = 0.0f;
#pragma unroll
  for (int k = 0; k < IN; ++k)
    acc = fmaf(h[(size_t)i * IN + k], W[k * OUT + c], acc);
  o[tid] = acc;
}

__global__ void k_softmax(const float* __restrict__ a, float* __restrict__ out) {
  const int i = blockIdx.x * blockDim.x + threadIdx.x;
  const float* __restrict__ p = a + (size_t)i * NCLS;
  float v[NCLS];
  float m = -3.0e38f;
#pragma unroll
  for (int c = 0; c < NCLS; ++c) { v[c] = p[c]; m = fmaxf(m, v[c]); }
  float s = 0.0f;
#pragma unroll
  for (int c = 0; c < NCLS; ++c) { v[c] = expf(v[c] - m); s += v[c]; }
  const float inv = 1.0f / s;
  float* __restrict__ q = out + (size_t)i * NCLS;
#pragma unroll
  for (int c = 0; c < NCLS; ++c) q[c] = v[c] * inv;
}

extern "C" void kernel_launch(void* const* d_in, const int* in_sizes, int n_in,
                              void* d_out, int out_size, void* d_ws, size_t ws_size,
                              hipStream_t stream) {
  const float* x  = (const float*)d_in[0];
  const int*   ei = (const int*)d_in[1];
  const float* W1 = (const float*)d_in[2];
  const float* b1 = (const float*)d_in[3];
  const float* W2 = (const float*)d_in[4];
  const float* b2 = (const float*)d_in[5];
  const float* W3 = (const float*)d_in[6];
  const float* b3 = (const float*)d_in[7];
  float* out = (float*)d_out;
  const int* e_src = ei;        // edge_index[0] = message sources
  const int* e_dst = ei + NE;   // edge_index[1] = aggregation targets

  char* base = (char*)d_ws;
  size_t cur_off = 0;
  auto alloc = [&](size_t bytes) -> void* {
    void* p = base + cur_off;
    cur_off = (cur_off + bytes + 255) & ~(size_t)255;
    return p;
  };
  float* part = (float*)alloc((size_t)SPLITK * NN * HID * sizeof(float));
  float* h36  = (float*)alloc((size_t)NN * HID * sizeof(float));
  float* a36  = (float*)alloc((size_t)NN * HID * sizeof(float));
  float* h16  = (float*)alloc((size_t)NN * NCLS * sizeof(float));
  float* a16  = (float*)alloc((size_t)NN * NCLS * sizeof(float));
  int*   cnt  = (int*)alloc(NN * sizeof(int));
  int*   offs = (int*)alloc((NN + 1) * sizeof(int));
  int*   curp = (int*)alloc(NN * sizeof(int));
  int*   es   = (int*)alloc(NE * sizeof(int));
  float* dis  = (float*)alloc(NN * sizeof(float));

  // CSR build (counting sort of edges by dst)
  k_zero_int<<<NN / 256, 256, 0, stream>>>(cnt, NN);
  k_count<<<NE / 256, 256, 0, stream>>>(e_dst, cnt);
  k_scan<<<1, 256, 0, stream>>>(cnt, offs, curp, dis);
  k_scatter<<<NE / 256, 256, 0, stream>>>(e_src, e_dst, curp, es);

  // layer 1
  k_gemm1<<<SPLITK * (NN / RT), 256, 0, stream>>>(x, W1, part);
  k_reduce<<<NN * HID / 256, 256, 0, stream>>>(part, h36, NN * HID);
  k_agg<HID, true><<<NN * HID / 256, 256, 0, stream>>>(h36, offs, es, dis, b1, a36);

  // layer 2
  k_mm<HID, HID><<<NN * HID / 256, 256, 0, stream>>>(a36, W2, h36);
  k_agg<HID, true><<<NN * HID / 256, 256, 0, stream>>>(h36, offs, es, dis, b2, a36);

  // layer 3 + softmax
  k_mm<HID, NCLS><<<NN * NCLS / 256, 256, 0, stream>>>(a36, W3, h16);
  k_agg<NCLS, false><<<NN * NCLS / 256, 256, 0, stream>>>(h16, offs, es, dis, b3, a16);
  k_softmax<<<NN / 256, 256, 0, stream>>>(a16, out);
}